// Round 1
// baseline (870.103 us; speedup 1.0000x reference)
//
#include <hip/hip_runtime.h>
#include <math.h>

#define S 2048
#define D 64
#define H 16

// ---------------------------------------------------------------------------
// Kernel 1: scores = Q @ K^T * 1/sqrt(64), per head.
// Tile 128x128, k-tile 32 (two passes over D=64), 256 threads, 8x8 per thread.
// Register blocking is STRIDED (row = ty+16*i, col = tx+16*j) so that the
// LDS b-read addresses (tx+16j)*33+k map to 16 distinct banks (33%32==1).
// ---------------------------------------------------------------------------
__global__ __launch_bounds__(256) void k_scores(const float* __restrict__ Q,
                                                const float* __restrict__ K,
                                                float* __restrict__ Sout) {
    __shared__ float Qs[128 * 33];
    __shared__ float Ks[128 * 33];
    const int h  = blockIdx.z;
    const int r0 = blockIdx.y * 128;
    const int c0 = blockIdx.x * 128;
    const int t  = threadIdx.x;
    const int tx = t & 15;
    const int ty = t >> 4;
    const float* Qh = Q + (size_t)h * S * D;
    const float* Kh = K + (size_t)h * S * D;

    float acc[8][8];
#pragma unroll
    for (int i = 0; i < 8; ++i)
#pragma unroll
        for (int j = 0; j < 8; ++j) acc[i][j] = 0.0f;

    const int srow = t >> 3;        // 0..31
    const int sc4  = (t & 7) * 4;   // 0,4,...,28

#pragma unroll
    for (int kt = 0; kt < 2; ++kt) {
        const int k0 = kt * 32;
        // stage Q tile [128 x 32] and K tile [128 x 32] into LDS (pad 33)
#pragma unroll
        for (int p = 0; p < 4; ++p) {
            const int r = srow + p * 32;
            float4 q4 = *(const float4*)(Qh + (size_t)(r0 + r) * D + k0 + sc4);
            float4 k4 = *(const float4*)(Kh + (size_t)(c0 + r) * D + k0 + sc4);
            Qs[r * 33 + sc4 + 0] = q4.x; Qs[r * 33 + sc4 + 1] = q4.y;
            Qs[r * 33 + sc4 + 2] = q4.z; Qs[r * 33 + sc4 + 3] = q4.w;
            Ks[r * 33 + sc4 + 0] = k4.x; Ks[r * 33 + sc4 + 1] = k4.y;
            Ks[r * 33 + sc4 + 2] = k4.z; Ks[r * 33 + sc4 + 3] = k4.w;
        }
        __syncthreads();
#pragma unroll
        for (int k = 0; k < 32; ++k) {
            float a[8], b[8];
#pragma unroll
            for (int i = 0; i < 8; ++i) a[i] = Qs[(ty + 16 * i) * 33 + k];
#pragma unroll
            for (int j = 0; j < 8; ++j) b[j] = Ks[(tx + 16 * j) * 33 + k];
#pragma unroll
            for (int i = 0; i < 8; ++i)
#pragma unroll
                for (int j = 0; j < 8; ++j) acc[i][j] += a[i] * b[j];
        }
        __syncthreads();
    }

    float* outbase = Sout + ((size_t)(h * S + r0)) * S + c0;
#pragma unroll
    for (int i = 0; i < 8; ++i) {
        const int r = ty + 16 * i;
#pragma unroll
        for (int j = 0; j < 8; ++j) {
            outbase[(size_t)r * S + tx + 16 * j] = acc[i][j] * 0.125f;
        }
    }
}

// ---------------------------------------------------------------------------
// Kernel 2: row softmax, in place on the attn region. One block per row.
// 2048 floats = 512 float4; 256 threads x 2 float4 each. Fully fp32.
// ---------------------------------------------------------------------------
__global__ __launch_bounds__(256) void k_softmax(float* __restrict__ P) {
    __shared__ float red[8];
    const size_t row = blockIdx.x;
    float* p = P + row * S;
    const int t = threadIdx.x;
    const int lane = t & 63;
    const int wave = t >> 6;

    float4 v0 = ((const float4*)p)[t];
    float4 v1 = ((const float4*)p)[t + 256];

    float m = fmaxf(fmaxf(fmaxf(v0.x, v0.y), fmaxf(v0.z, v0.w)),
                    fmaxf(fmaxf(v1.x, v1.y), fmaxf(v1.z, v1.w)));
#pragma unroll
    for (int o = 32; o > 0; o >>= 1) m = fmaxf(m, __shfl_xor(m, o));
    if (lane == 0) red[wave] = m;
    __syncthreads();
    m = fmaxf(fmaxf(red[0], red[1]), fmaxf(red[2], red[3]));

    v0.x = __expf(v0.x - m); v0.y = __expf(v0.y - m);
    v0.z = __expf(v0.z - m); v0.w = __expf(v0.w - m);
    v1.x = __expf(v1.x - m); v1.y = __expf(v1.y - m);
    v1.z = __expf(v1.z - m); v1.w = __expf(v1.w - m);

    float ssum = v0.x + v0.y + v0.z + v0.w + v1.x + v1.y + v1.z + v1.w;
#pragma unroll
    for (int o = 32; o > 0; o >>= 1) ssum += __shfl_xor(ssum, o);
    if (lane == 0) red[4 + wave] = ssum;
    __syncthreads();
    const float l = red[4] + red[5] + red[6] + red[7];
    const float inv = 1.0f / l;

    v0.x *= inv; v0.y *= inv; v0.z *= inv; v0.w *= inv;
    v1.x *= inv; v1.y *= inv; v1.z *= inv; v1.w *= inv;
    ((float4*)p)[t] = v0;
    ((float4*)p)[t + 256] = v1;
}

// ---------------------------------------------------------------------------
// Kernel 3: context = P @ V per head. Block = 64 rows x full D=64.
// k-tiles of 32. P staged in LDS (pad 33), V tile [32x64] read as float4.
// Thread: tx = d4 index (4 d-values via float4), ty+16i = 4 rows.
// ---------------------------------------------------------------------------
__global__ __launch_bounds__(256) void k_context(const float* __restrict__ P,
                                                 const float* __restrict__ V,
                                                 float* __restrict__ C) {
    __shared__ float Ps[64 * 33];
    __shared__ float Vs[32 * 64];
    const int r0 = blockIdx.x * 64;           // global row 0..32767
    const int h  = blockIdx.x >> 5;           // r0 / 2048
    const float* Vh = V + (size_t)h * S * D;
    const int t  = threadIdx.x;
    const int tx = t & 15;
    const int ty = t >> 4;

    float4 acc[4];
#pragma unroll
    for (int i = 0; i < 4; ++i) { acc[i].x = 0.f; acc[i].y = 0.f; acc[i].z = 0.f; acc[i].w = 0.f; }

    for (int kt = 0; kt < 64; ++kt) {
        const int k0 = kt * 32;
        // stage P tile [64 x 32]
#pragma unroll
        for (int pp = 0; pp < 2; ++pp) {
            const int f4  = t + pp * 256;     // 0..511
            const int row = f4 >> 3;          // 0..63
            const int c4  = (f4 & 7) * 4;     // 0..28
            float4 x = *(const float4*)(P + (size_t)(r0 + row) * S + k0 + c4);
            Ps[row * 33 + c4 + 0] = x.x; Ps[row * 33 + c4 + 1] = x.y;
            Ps[row * 33 + c4 + 2] = x.z; Ps[row * 33 + c4 + 3] = x.w;
        }
        // stage V tile [32 x 64]
#pragma unroll
        for (int pp = 0; pp < 2; ++pp) {
            const int f4  = t + pp * 256;     // 0..511
            const int row = f4 >> 4;          // 0..31
            const int c4  = (f4 & 15) * 4;    // 0..60
            *(float4*)&Vs[row * 64 + c4] =
                *(const float4*)(Vh + (size_t)(k0 + row) * D + c4);
        }
        __syncthreads();
#pragma unroll
        for (int k = 0; k < 32; ++k) {
            const float4 v = *(const float4*)&Vs[k * 64 + tx * 4];
#pragma unroll
            for (int i = 0; i < 4; ++i) {
                const float pv = Ps[(ty + 16 * i) * 33 + k];
                acc[i].x += pv * v.x; acc[i].y += pv * v.y;
                acc[i].z += pv * v.z; acc[i].w += pv * v.w;
            }
        }
        __syncthreads();
    }

#pragma unroll
    for (int i = 0; i < 4; ++i) {
        *(float4*)(C + (size_t)(r0 + ty + 16 * i) * D + tx * 4) = acc[i];
    }
}

extern "C" void kernel_launch(void* const* d_in, const int* in_sizes, int n_in,
                              void* d_out, int out_size, void* d_ws, size_t ws_size,
                              hipStream_t stream) {
    (void)in_sizes; (void)n_in; (void)d_ws; (void)ws_size; (void)out_size;
    const float* Q = (const float*)d_in[0];
    const float* K = (const float*)d_in[1];
    const float* V = (const float*)d_in[2];
    float* ctx  = (float*)d_out;                          // [16,2048,64]
    float* attn = (float*)d_out + (size_t)H * S * D;      // [16,2048,2048]

    // 1) raw scores into the attn output region (used as scratch)
    k_scores<<<dim3(16, 16, 16), 256, 0, stream>>>(Q, K, attn);
    // 2) softmax in place
    k_softmax<<<dim3(H * S), 256, 0, stream>>>(attn);
    // 3) context = attn @ V
    k_context<<<dim3(H * S / 64), 256, 0, stream>>>(attn, V, ctx);
}

// Round 2
// 434.827 us; speedup vs baseline: 2.0010x; 2.0010x over previous
//
#include <hip/hip_runtime.h>
#include <math.h>

#define S 2048
#define D 64
#define H 16
#define BR 64              // Q rows per block
#define BC 64              // K cols per tile
#define NIT (S / BC)       // 32 K-tiles
#define KSTR 72            // LDS row stride in bf16 elems (multiple of 8 for b128, 2-way banks only)

typedef __attribute__((ext_vector_type(8))) short bf16x8;
typedef __attribute__((ext_vector_type(4))) float f32x4;

__device__ __forceinline__ unsigned short f2bf(float x) {
    unsigned u = __float_as_uint(x);
    u += 0x7fffu + ((u >> 16) & 1u);          // RTNE
    return (unsigned short)(u >> 16);
}
__device__ __forceinline__ float bf2f(unsigned short h) {
    return __uint_as_float(((unsigned)h) << 16);
}

// Fused attention with materialized attn output.
// Per block: 64 Q-rows of one head. Pass A: QK^T (bf16 MFMA) -> row sums of exp.
// Pass B: recompute QK^T, write normalized attn (fp32), P@V via hi/lo-split bf16 MFMA.
__global__ __launch_bounds__(256, 2)
void k_attn_fused(const float* __restrict__ Q, const float* __restrict__ K,
                  const float* __restrict__ V, float* __restrict__ ctx,
                  float* __restrict__ attn) {
    __shared__ __align__(16) unsigned short Qs[BR * KSTR];    // 9.2 KB
    __shared__ __align__(16) unsigned short Ks[BC * KSTR];    // 9.2 KB
    __shared__ __align__(16) unsigned short Vthi[D * KSTR];   // V^T hi: [d][k]
    __shared__ __align__(16) unsigned short Vtlo[D * KSTR];   // V^T lo
    __shared__ __align__(16) unsigned short Phi[BR * KSTR];   // P hi (A-layout staging)
    __shared__ __align__(16) unsigned short Plo[BR * KSTR];   // P lo
    // total 55.3 KB -> 2 blocks/CU

    const int h  = blockIdx.y;
    const int r0 = blockIdx.x * BR;
    const int t  = threadIdx.x;
    const int w    = t >> 6;        // wave 0..3 -> rows [w*16, w*16+16)
    const int lane = t & 63;
    const int l16  = lane & 15;
    const int quad = lane >> 4;

    const float* Qh = Q + (size_t)h * S * D;
    const float* Kh = K + (size_t)h * S * D;
    const float* Vh = V + (size_t)h * S * D;

    // ---- stage Q tile (64x64 fp32 -> bf16 LDS), coalesced float4 ----
#pragma unroll
    for (int p = 0; p < 4; ++p) {
        int idx = t + p * 256;                 // 0..1023 float4s
        int r = idx >> 4, c4 = (idx & 15) * 4;
        float4 v = *(const float4*)(Qh + (size_t)(r0 + r) * D + c4);
        *(ushort4*)&Qs[r * KSTR + c4] =
            make_ushort4(f2bf(v.x), f2bf(v.y), f2bf(v.z), f2bf(v.w));
    }
    __syncthreads();

    // persistent Q A-frags: A[m=lane&15][k=quad*8+j], k-steps 0/1 cover D=64
    bf16x8 aq[2];
    aq[0] = *(const bf16x8*)&Qs[(w * 16 + l16) * KSTR + 0 * 32 + quad * 8];
    aq[1] = *(const bf16x8*)&Qs[(w * 16 + l16) * KSTR + 1 * 32 + quad * 8];

    const f32x4 zero4 = {0.f, 0.f, 0.f, 0.f};
    float lsum[4] = {0.f, 0.f, 0.f, 0.f};      // row = w*16 + quad*4 + reg

    // =================== Pass A: denominators ===================
    for (int kt = 0; kt < NIT; ++kt) {
#pragma unroll
        for (int p = 0; p < 4; ++p) {
            int idx = t + p * 256;
            int r = idx >> 4, c4 = (idx & 15) * 4;
            float4 v = *(const float4*)(Kh + (size_t)(kt * BC + r) * D + c4);
            *(ushort4*)&Ks[r * KSTR + c4] =
                make_ushort4(f2bf(v.x), f2bf(v.y), f2bf(v.z), f2bf(v.w));
        }
        __syncthreads();

        f32x4 acc[4] = {zero4, zero4, zero4, zero4};
#pragma unroll
        for (int ks = 0; ks < 2; ++ks)
#pragma unroll
            for (int cs = 0; cs < 4; ++cs) {
                bf16x8 bk = *(const bf16x8*)&Ks[(cs * 16 + l16) * KSTR + ks * 32 + quad * 8];
                acc[cs] = __builtin_amdgcn_mfma_f32_16x16x32_bf16(aq[ks], bk, acc[cs], 0, 0, 0);
            }
#pragma unroll
        for (int reg = 0; reg < 4; ++reg) {
            float e = __expf(acc[0][reg] * 0.125f) + __expf(acc[1][reg] * 0.125f)
                    + __expf(acc[2][reg] * 0.125f) + __expf(acc[3][reg] * 0.125f);
            e += __shfl_xor(e, 1); e += __shfl_xor(e, 2);
            e += __shfl_xor(e, 4); e += __shfl_xor(e, 8);
            lsum[reg] += e;
        }
        __syncthreads();
    }

    float linv[4];
#pragma unroll
    for (int reg = 0; reg < 4; ++reg) linv[reg] = 1.0f / lsum[reg];

    // =================== Pass B: attn write + P@V ===================
    f32x4 cacc[4] = {zero4, zero4, zero4, zero4};   // ctx: rows as C-layout, cols vs*16+l16
    for (int kt = 0; kt < NIT; ++kt) {
        // stage K tile
#pragma unroll
        for (int p = 0; p < 4; ++p) {
            int idx = t + p * 256;
            int r = idx >> 4, c4 = (idx & 15) * 4;
            float4 v = *(const float4*)(Kh + (size_t)(kt * BC + r) * D + c4);
            *(ushort4*)&Ks[r * KSTR + c4] =
                make_ushort4(f2bf(v.x), f2bf(v.y), f2bf(v.z), f2bf(v.w));
        }
        // stage V tile transposed, hi/lo split: Vt[d][k]
#pragma unroll
        for (int p = 0; p < 4; ++p) {
            int idx = t + p * 256;
            int r = idx >> 4, c4 = (idx & 15) * 4;   // r = k index, c4 = d
            float4 v = *(const float4*)(Vh + (size_t)(kt * BC + r) * D + c4);
            float vv[4] = {v.x, v.y, v.z, v.w};
#pragma unroll
            for (int c = 0; c < 4; ++c) {
                unsigned short hi = f2bf(vv[c]);
                Vthi[(c4 + c) * KSTR + r] = hi;
                Vtlo[(c4 + c) * KSTR + r] = f2bf(vv[c] - bf2f(hi));
            }
        }
        __syncthreads();

        // recompute S tile
        f32x4 acc[4] = {zero4, zero4, zero4, zero4};
#pragma unroll
        for (int ks = 0; ks < 2; ++ks)
#pragma unroll
            for (int cs = 0; cs < 4; ++cs) {
                bf16x8 bk = *(const bf16x8*)&Ks[(cs * 16 + l16) * KSTR + ks * 32 + quad * 8];
                acc[cs] = __builtin_amdgcn_mfma_f32_16x16x32_bf16(aq[ks], bk, acc[cs], 0, 0, 0);
            }

        // normalize, write attn, stage P (hi/lo) for the A-operand reload
        const int gr_base = r0 + w * 16 + quad * 4;
        const int lr_base = w * 16 + quad * 4;
#pragma unroll
        for (int cs = 0; cs < 4; ++cs)
#pragma unroll
            for (int reg = 0; reg < 4; ++reg) {
                float pv = __expf(acc[cs][reg] * 0.125f) * linv[reg];
                attn[((size_t)h * S + gr_base + reg) * S + (size_t)kt * BC + cs * 16 + l16] = pv;
                unsigned short hi = f2bf(pv);
                Phi[(lr_base + reg) * KSTR + cs * 16 + l16] = hi;
                Plo[(lr_base + reg) * KSTR + cs * 16 + l16] = f2bf(pv - bf2f(hi));
            }
        __syncthreads();

        // P @ V : (Phi+Plo)(Vhi+Vlo) ~= Phi*Vhi + Phi*Vlo + Plo*Vhi
#pragma unroll
        for (int ks = 0; ks < 2; ++ks) {
            bf16x8 ah = *(const bf16x8*)&Phi[(w * 16 + l16) * KSTR + ks * 32 + quad * 8];
            bf16x8 al = *(const bf16x8*)&Plo[(w * 16 + l16) * KSTR + ks * 32 + quad * 8];
#pragma unroll
            for (int vs = 0; vs < 4; ++vs) {
                bf16x8 bh = *(const bf16x8*)&Vthi[(vs * 16 + l16) * KSTR + ks * 32 + quad * 8];
                bf16x8 bl = *(const bf16x8*)&Vtlo[(vs * 16 + l16) * KSTR + ks * 32 + quad * 8];
                cacc[vs] = __builtin_amdgcn_mfma_f32_16x16x32_bf16(ah, bh, cacc[vs], 0, 0, 0);
                cacc[vs] = __builtin_amdgcn_mfma_f32_16x16x32_bf16(ah, bl, cacc[vs], 0, 0, 0);
                cacc[vs] = __builtin_amdgcn_mfma_f32_16x16x32_bf16(al, bh, cacc[vs], 0, 0, 0);
            }
        }
        __syncthreads();
    }

    // epilogue: ctx store (fp32)
    const int gr_base = r0 + w * 16 + quad * 4;
#pragma unroll
    for (int vs = 0; vs < 4; ++vs)
#pragma unroll
        for (int reg = 0; reg < 4; ++reg)
            ctx[((size_t)h * S + gr_base + reg) * D + vs * 16 + l16] = cacc[vs][reg];
}

extern "C" void kernel_launch(void* const* d_in, const int* in_sizes, int n_in,
                              void* d_out, int out_size, void* d_ws, size_t ws_size,
                              hipStream_t stream) {
    (void)in_sizes; (void)n_in; (void)d_ws; (void)ws_size; (void)out_size;
    const float* Q = (const float*)d_in[0];
    const float* K = (const float*)d_in[1];
    const float* V = (const float*)d_in[2];
    float* ctx  = (float*)d_out;                          // [16,2048,64]
    float* attn = (float*)d_out + (size_t)H * S * D;      // [16,2048,2048]

    k_attn_fused<<<dim3(S / BR, H), 256, 0, stream>>>(Q, K, V, ctx, attn);
}